// Round 8
// baseline (835.915 us; speedup 1.0000x reference)
//
#include <hip/hip_runtime.h>

#define N_SP 4096   // H*W
#define C_IN 512
#define CQ   64

typedef __attribute__((ext_vector_type(8))) short bf16x8;
typedef __attribute__((ext_vector_type(4))) float f32x4;
typedef unsigned short ushort_t;

__device__ __forceinline__ unsigned int f2bf(float f) {
    unsigned int u = __float_as_uint(f);
    u += 0x7FFFu + ((u >> 16) & 1u);   // RNE
    return u >> 16;
}

// ---------------------------------------------------------------------------
// Kernel A: transpose+convert x: fp32 [b][c][n] -> bf16 xT [b][n][c].
// ---------------------------------------------------------------------------
__global__ __launch_bounds__(256, 4)
void transpose_x(const float* __restrict__ x, ushort_t* __restrict__ xT)
{
    const int tid = threadIdx.x;
    const int nt = blockIdx.x, ct = blockIdx.y, b = blockIdx.z;
    __shared__ float Tl[64][65];
    {
        const int row = tid >> 2, nc = (tid & 3) * 16;
        const float* src = x + ((size_t)(b*C_IN + ct*64 + row))*N_SP + nt*64 + nc;
        #pragma unroll
        for (int q = 0; q < 4; ++q) {
            float4 v = *reinterpret_cast<const float4*>(src + q*4);
            Tl[row][nc + q*4 + 0] = v.x; Tl[row][nc + q*4 + 1] = v.y;
            Tl[row][nc + q*4 + 2] = v.z; Tl[row][nc + q*4 + 3] = v.w;
        }
    }
    __syncthreads();
    {
        const int nrow = tid >> 2, ck = (tid & 3) * 16;
        unsigned int wds[8];
        #pragma unroll
        for (int k = 0; k < 16; k += 2)
            wds[k >> 1] = f2bf(Tl[ck + k][nrow]) | (f2bf(Tl[ck + k + 1][nrow]) << 16);
        ushort_t* d = xT + ((size_t)(b*N_SP + nt*64 + nrow))*C_IN + ct*64 + ck;
        reinterpret_cast<uint4*>(d)[0] = make_uint4(wds[0], wds[1], wds[2], wds[3]);
        reinterpret_cast<uint4*>(d)[1] = make_uint4(wds[4], wds[5], wds[6], wds[7]);
    }
}

// ---------------------------------------------------------------------------
// Kernel B: convert weights fp32 -> bf16.
// ---------------------------------------------------------------------------
__global__ __launch_bounds__(256, 4)
void convert_w(const float* __restrict__ Wq, const float* __restrict__ Wk,
               const float* __restrict__ Wv,
               ushort_t* __restrict__ Wqb, ushort_t* __restrict__ Wkb,
               ushort_t* __restrict__ Wvb)
{
    const int i4 = (blockIdx.x*256 + threadIdx.x) * 4;
    const float* src; ushort_t* dst; int off;
    if (i4 < 32768)       { src = Wq; dst = Wqb; off = i4; }
    else if (i4 < 65536)  { src = Wk; dst = Wkb; off = i4 - 32768; }
    else                  { src = Wv; dst = Wvb; off = i4 - 65536; }
    float4 v = *reinterpret_cast<const float4*>(src + off);
    ushort4 h;
    h.x = (ushort_t)f2bf(v.x); h.y = (ushort_t)f2bf(v.y);
    h.z = (ushort_t)f2bf(v.z); h.w = (ushort_t)f2bf(v.w);
    *reinterpret_cast<ushort4*>(dst + off) = h;
}

// ---------------------------------------------------------------------------
// Kernel C: MFMA QKV projection (unchanged from R5 — passed).
// ---------------------------------------------------------------------------
__global__ __launch_bounds__(256, 4)
void proj_mfma(const ushort_t* __restrict__ xT,
               const ushort_t* __restrict__ Wqb, const ushort_t* __restrict__ Wkb,
               const ushort_t* __restrict__ Wvb,
               ushort_t* __restrict__ Qt, ushort_t* __restrict__ Kt,
               ushort_t* __restrict__ Vb)
{
    const int tid = threadIdx.x;
    const int lane = tid & 63, w = tid >> 6;
    const int g = lane >> 4, c16 = lane & 15;
    const int nt = blockIdx.x, mt = blockIdx.y, b = blockIdx.z;
    const int n0 = nt * 128;
    const int kind = (mt == 0) ? 0 : (mt == 1) ? 1 : 2;
    const int wrow0 = (kind == 2) ? (mt - 2) * 64 : 0;
    const ushort_t* Wsrc = (kind == 0) ? Wqb : (kind == 1) ? Wkb : (Wvb + (size_t)wrow0*C_IN);

    __shared__ ushort_t Wl[64*64];
    __shared__ ushort_t Xl[128*64];

    f32x4 acc[8];
    #pragma unroll
    for (int i = 0; i < 8; ++i) acc[i] = (f32x4){0.f,0.f,0.f,0.f};

    const int wrow = tid >> 2, wbc = (tid & 3) * 32;
    const int xrow = tid >> 1, xbc = (tid & 1) * 64;
    const ushort_t* wsrcp = Wsrc + (size_t)wrow*C_IN + wbc/2;
    const ushort_t* xsrcp = xT + ((size_t)(b*N_SP + n0 + xrow))*C_IN + xbc/2;
    char* wdst = (char*)Wl + wrow*128;
    char* xdst = (char*)Xl + xrow*128;
    const int wsz = (wrow & 7) << 4;
    const int xsz = (xrow & 7) << 4;

    uint4 wr[2], xr[4];
    #pragma unroll
    for (int j = 0; j < 2; ++j) wr[j] = *reinterpret_cast<const uint4*>(wsrcp + j*8);
    #pragma unroll
    for (int j = 0; j < 4; ++j) xr[j] = *reinterpret_cast<const uint4*>(xsrcp + j*8);

    const int aswz = (c16 & 7) << 4;

    for (int ks = 0; ks < 8; ++ks) {
        if (ks) __syncthreads();
        #pragma unroll
        for (int j = 0; j < 2; ++j)
            *reinterpret_cast<uint4*>(wdst + ((wbc + j*16) ^ wsz)) = wr[j];
        #pragma unroll
        for (int j = 0; j < 4; ++j)
            *reinterpret_cast<uint4*>(xdst + ((xbc + j*16) ^ xsz)) = xr[j];
        if (ks + 1 < 8) {
            const int k0 = (ks + 1) * 64;
            #pragma unroll
            for (int j = 0; j < 2; ++j) wr[j] = *reinterpret_cast<const uint4*>(wsrcp + k0 + j*8);
            #pragma unroll
            for (int j = 0; j < 4; ++j) xr[j] = *reinterpret_cast<const uint4*>(xsrcp + k0 + j*8);
        }
        __syncthreads();

        __builtin_amdgcn_s_setprio(1);
        if (kind < 2) {
            bf16x8 af[2][2], bfr[4][2];
            #pragma unroll
            for (int m2 = 0; m2 < 2; ++m2)
                #pragma unroll
                for (int kh = 0; kh < 2; ++kh)
                    af[m2][kh] = *reinterpret_cast<const bf16x8*>(
                        (char*)Xl + (w*32 + m2*16 + c16)*128 + ((kh*64 + g*16) ^ aswz));
            #pragma unroll
            for (int ot = 0; ot < 4; ++ot)
                #pragma unroll
                for (int kh = 0; kh < 2; ++kh)
                    bfr[ot][kh] = *reinterpret_cast<const bf16x8*>(
                        (char*)Wl + (ot*16 + c16)*128 + ((kh*64 + g*16) ^ aswz));
            #pragma unroll
            for (int m2 = 0; m2 < 2; ++m2)
                #pragma unroll
                for (int ot = 0; ot < 4; ++ot) {
                    acc[m2*4+ot] = __builtin_amdgcn_mfma_f32_16x16x32_bf16(af[m2][0], bfr[ot][0], acc[m2*4+ot], 0, 0, 0);
                    acc[m2*4+ot] = __builtin_amdgcn_mfma_f32_16x16x32_bf16(af[m2][1], bfr[ot][1], acc[m2*4+ot], 0, 0, 0);
                }
        } else {
            bf16x8 af[4][2], bfr[2][2];
            #pragma unroll
            for (int ct = 0; ct < 4; ++ct)
                #pragma unroll
                for (int kh = 0; kh < 2; ++kh)
                    af[ct][kh] = *reinterpret_cast<const bf16x8*>(
                        (char*)Wl + (ct*16 + c16)*128 + ((kh*64 + g*16) ^ aswz));
            #pragma unroll
            for (int n2 = 0; n2 < 2; ++n2)
                #pragma unroll
                for (int kh = 0; kh < 2; ++kh)
                    bfr[n2][kh] = *reinterpret_cast<const bf16x8*>(
                        (char*)Xl + (w*32 + n2*16 + c16)*128 + ((kh*64 + g*16) ^ aswz));
            #pragma unroll
            for (int ct = 0; ct < 4; ++ct)
                #pragma unroll
                for (int n2 = 0; n2 < 2; ++n2) {
                    acc[ct*2+n2] = __builtin_amdgcn_mfma_f32_16x16x32_bf16(af[ct][0], bfr[n2][0], acc[ct*2+n2], 0, 0, 0);
                    acc[ct*2+n2] = __builtin_amdgcn_mfma_f32_16x16x32_bf16(af[ct][1], bfr[n2][1], acc[ct*2+n2], 0, 0, 0);
                }
        }
        __builtin_amdgcn_s_setprio(0);
    }

    if (kind < 2) {
        ushort_t* O = (kind == 0 ? Qt : Kt) + (size_t)b*N_SP*CQ;
        #pragma unroll
        for (int m2 = 0; m2 < 2; ++m2)
            #pragma unroll
            for (int ot = 0; ot < 4; ++ot)
                #pragma unroll
                for (int q = 0; q < 4; ++q) {
                    const int n = n0 + w*32 + m2*16 + g*4 + q;
                    O[(size_t)n*CQ + ot*16 + c16] = (ushort_t)f2bf(acc[m2*4+ot][q]);
                }
    } else {
        #pragma unroll
        for (int ct = 0; ct < 4; ++ct)
            #pragma unroll
            for (int n2 = 0; n2 < 2; ++n2)
                #pragma unroll
                for (int q = 0; q < 4; ++q) {
                    const int c = wrow0 + ct*16 + g*4 + q;
                    const int n = n0 + w*32 + n2*16 + c16;
                    Vb[((size_t)b*C_IN + c)*N_SP + n] = (ushort_t)f2bf(acc[ct*2+n2][q]);
                }
    }
}

// ---------------------------------------------------------------------------
// Kernel D: barrier-free 1-wave flash attention + gamma*out + x.
// Block = 1 wave (64 thr): 16 queries (lane&15) x 128 channels.
// K/Q/V fragments load DIRECTLY from global (64B-line coalesced, L2-resident;
// LDS staging + barriers removed entirely). Only LDS: private 2KB swizzled
// P-transpose buffer (same-wave roundtrip, lgkmcnt(0)+sched_barrier).
// Grid (256,4,4)=4096 independent waves -> latency hidden by TLP, no
// block-wide lockstep.
// ---------------------------------------------------------------------------
__global__ __launch_bounds__(64, 4)
void attn_mfma(const float* __restrict__ x,
               const ushort_t* __restrict__ Qt,
               const ushort_t* __restrict__ Kt,
               const ushort_t* __restrict__ Vb,
               const float* __restrict__ gamma_p,
               float* __restrict__ out)
{
    const int lane = threadIdx.x & 63;
    const int g    = lane >> 4;
    const int c16  = lane & 15;

    const int it  = blockIdx.x;      // 256 query tiles of 16
    const int c0  = blockIdx.y * 128;
    const int b   = blockIdx.z;
    const int i0g = it * 16;

    __shared__ ushort_t Pl[16*64];   // 2 KB, swizzled rows of 128 B

    const int aswz = (c16 & 7) << 4;
    const int arow = c16 * 128;

    // Q fragments, direct from global (row = this lane's query)
    const ushort_t* Qrow = Qt + ((size_t)b*N_SP + i0g + c16)*CQ;
    const bf16x8 qf0 = *reinterpret_cast<const bf16x8*>(Qrow + g*8);
    const bf16x8 qf1 = *reinterpret_cast<const bf16x8*>(Qrow + 32 + g*8);

    float m_run = -1e30f, l_run = 0.f;
    f32x4 acc[8];
    #pragma unroll
    for (int ct = 0; ct < 8; ++ct) acc[ct] = (f32x4){0.f, 0.f, 0.f, 0.f};

    const ushort_t* Kbase = Kt + (size_t)b*N_SP*CQ;
    const ushort_t* Vrow  = Vb + ((size_t)b*C_IN + c0 + c16)*N_SP + g*8;

    for (int jb = 0; jb < N_SP; jb += 64) {
        // ---- S^T = K·Q^T, K fragments direct from global ----
        f32x4 sf[4];
        #pragma unroll
        for (int jt = 0; jt < 4; ++jt) {
            const ushort_t* Krow = Kbase + (size_t)(jb + jt*16 + c16)*CQ;
            const bf16x8 kf0 = *reinterpret_cast<const bf16x8*>(Krow + g*8);
            const bf16x8 kf1 = *reinterpret_cast<const bf16x8*>(Krow + 32 + g*8);
            f32x4 z = (f32x4){0.f, 0.f, 0.f, 0.f};
            z = __builtin_amdgcn_mfma_f32_16x16x32_bf16(kf0, qf0, z, 0, 0, 0);
            z = __builtin_amdgcn_mfma_f32_16x16x32_bf16(kf1, qf1, z, 0, 0, 0);
            sf[jt] = z;
        }

        // ---- online softmax; lane owns query i0g + c16 (16 j-values) ----
        float cmax = sf[0][0];
        #pragma unroll
        for (int jt = 0; jt < 4; ++jt)
            #pragma unroll
            for (int q = 0; q < 4; ++q) cmax = fmaxf(cmax, sf[jt][q]);
        cmax = fmaxf(cmax, __shfl_xor(cmax, 16));
        cmax = fmaxf(cmax, __shfl_xor(cmax, 32));
        const float mn = fmaxf(m_run, cmax);
        const float rr = __expf(m_run - mn);
        float csum = 0.f;
        #pragma unroll
        for (int jt = 0; jt < 4; ++jt)
            #pragma unroll
            for (int q = 0; q < 4; ++q) {
                const float p = __expf(sf[jt][q] - mn);
                csum += p;
                sf[jt][q] = p;
            }
        csum += __shfl_xor(csum, 16);
        csum += __shfl_xor(csum, 32);
        l_run = l_run * rr + csum;
        m_run = mn;

        // ---- P -> bf16 -> private LDS (A-frag layout), same-wave roundtrip ----
        #pragma unroll
        for (int jt = 0; jt < 4; ++jt) {
            uint2 pk;
            pk.x = f2bf(sf[jt][0]) | (f2bf(sf[jt][1]) << 16);
            pk.y = f2bf(sf[jt][2]) | (f2bf(sf[jt][3]) << 16);
            *reinterpret_cast<uint2*>((char*)Pl + arow + ((jt*32 + g*8) ^ aswz)) = pk;
        }
        __asm__ volatile("s_waitcnt lgkmcnt(0)" ::: "memory");
        __builtin_amdgcn_sched_barrier(0);
        const bf16x8 pa0 = *reinterpret_cast<const bf16x8*>(
            (const char*)Pl + arow + ((g*16) ^ aswz));
        const bf16x8 pa1 = *reinterpret_cast<const bf16x8*>(
            (const char*)Pl + arow + ((64 + g*16) ^ aswz));

        // ---- rescale O (C/D rows are queries g*4+q) ----
        float rb[4];
        #pragma unroll
        for (int q = 0; q < 4; ++q) rb[q] = __shfl(rr, g*4 + q);
        #pragma unroll
        for (int ct = 0; ct < 8; ++ct)
            #pragma unroll
            for (int q = 0; q < 4; ++q) acc[ct][q] *= rb[q];

        // ---- O += P·V^T, V fragments direct from global ----
        #pragma unroll
        for (int ct = 0; ct < 8; ++ct) {
            const bf16x8 v0 = *reinterpret_cast<const bf16x8*>(
                Vrow + (size_t)(ct*16)*N_SP + jb);
            acc[ct] = __builtin_amdgcn_mfma_f32_16x16x32_bf16(pa0, v0, acc[ct], 0, 0, 0);
        }
        #pragma unroll
        for (int ct = 0; ct < 8; ++ct) {
            const bf16x8 v1 = *reinterpret_cast<const bf16x8*>(
                Vrow + (size_t)(ct*16)*N_SP + jb + 32);
            acc[ct] = __builtin_amdgcn_mfma_f32_16x16x32_bf16(pa1, v1, acc[ct], 0, 0, 0);
        }
    }

    // ---- epilogue: out = gamma*O/l + x ----
    const float gm = gamma_p[0];
    const float li = 1.0f / l_run;
    float lb[4];
    #pragma unroll
    for (int q = 0; q < 4; ++q) lb[q] = __shfl(li, g*4 + q);
    #pragma unroll
    for (int ct = 0; ct < 8; ++ct) {
        const size_t base = ((size_t)b*C_IN + c0 + ct*16 + c16)*N_SP + i0g + g*4;
        const float4 xv = *reinterpret_cast<const float4*>(x + base);
        float4 ov;
        ov.x = fmaf(gm, acc[ct][0]*lb[0], xv.x);
        ov.y = fmaf(gm, acc[ct][1]*lb[1], xv.y);
        ov.z = fmaf(gm, acc[ct][2]*lb[2], xv.z);
        ov.w = fmaf(gm, acc[ct][3]*lb[3], xv.w);
        *reinterpret_cast<float4*>(out + base) = ov;
    }
}

extern "C" void kernel_launch(void* const* d_in, const int* in_sizes, int n_in,
                              void* d_out, int out_size, void* d_ws, size_t ws_size,
                              hipStream_t stream)
{
    (void)in_sizes; (void)n_in; (void)out_size; (void)ws_size;
    const float* x  = (const float*)d_in[0];
    const float* Wq = (const float*)d_in[1];
    const float* Wk = (const float*)d_in[2];
    const float* Wv = (const float*)d_in[3];
    const float* gm = (const float*)d_in[4];
    float* out = (float*)d_out;

    // ws layout (shorts): xT 16.8M | Qt 2M | Kt 2M | V 16.8M | Wqb | Wkb | Wvb
    ushort_t* xT  = (ushort_t*)d_ws;
    ushort_t* Qt  = xT  + (size_t)4*N_SP*C_IN;
    ushort_t* Kt  = Qt  + (size_t)4*N_SP*CQ;
    ushort_t* Vb  = Kt  + (size_t)4*N_SP*CQ;
    ushort_t* Wqb = Vb  + (size_t)4*C_IN*N_SP;
    ushort_t* Wkb = Wqb + (size_t)CQ*C_IN;
    ushort_t* Wvb = Wkb + (size_t)CQ*C_IN;

    dim3 gA(64, 8, 4);
    transpose_x<<<gA, 256, 0, stream>>>(x, xT);
    convert_w<<<320, 256, 0, stream>>>(Wq, Wk, Wv, Wqb, Wkb, Wvb);
    dim3 gC(32, 10, 4);
    proj_mfma<<<gC, 256, 0, stream>>>(xT, Wqb, Wkb, Wvb, Qt, Kt, Vb);
    dim3 gD(256, 4, 4);
    attn_mfma<<<gD, 64, 0, stream>>>(x, Qt, Kt, Vb, gm, out);
}

// Round 11
// 372.102 us; speedup vs baseline: 2.2465x; 2.2465x over previous
//
#include <hip/hip_runtime.h>

#define N_SP 4096   // H*W
#define C_IN 512
#define CQ   64

typedef __attribute__((ext_vector_type(8))) short bf16x8;
typedef __attribute__((ext_vector_type(4))) float f32x4;
typedef unsigned short ushort_t;

__device__ __forceinline__ unsigned int f2bf(float f) {
    unsigned int u = __float_as_uint(f);
    u += 0x7FFFu + ((u >> 16) & 1u);   // RNE
    return u >> 16;
}

__device__ __forceinline__ void dma16(const void* g, void* l) {
    __builtin_amdgcn_global_load_lds((const __attribute__((address_space(1))) unsigned int*)g,
                                     (__attribute__((address_space(3))) unsigned int*)l,
                                     16, 0, 0);
}

// ---------------------------------------------------------------------------
// Kernel A: transpose+convert x: fp32 [b][c][n] -> bf16 xT [b][n][c].
// ---------------------------------------------------------------------------
__global__ __launch_bounds__(256, 4)
void transpose_x(const float* __restrict__ x, ushort_t* __restrict__ xT)
{
    const int tid = threadIdx.x;
    const int nt = blockIdx.x, ct = blockIdx.y, b = blockIdx.z;
    __shared__ float Tl[64][65];
    {
        const int row = tid >> 2, nc = (tid & 3) * 16;
        const float* src = x + ((size_t)(b*C_IN + ct*64 + row))*N_SP + nt*64 + nc;
        #pragma unroll
        for (int q = 0; q < 4; ++q) {
            float4 v = *reinterpret_cast<const float4*>(src + q*4);
            Tl[row][nc + q*4 + 0] = v.x; Tl[row][nc + q*4 + 1] = v.y;
            Tl[row][nc + q*4 + 2] = v.z; Tl[row][nc + q*4 + 3] = v.w;
        }
    }
    __syncthreads();
    {
        const int nrow = tid >> 2, ck = (tid & 3) * 16;
        unsigned int wds[8];
        #pragma unroll
        for (int k = 0; k < 16; k += 2)
            wds[k >> 1] = f2bf(Tl[ck + k][nrow]) | (f2bf(Tl[ck + k + 1][nrow]) << 16);
        ushort_t* d = xT + ((size_t)(b*N_SP + nt*64 + nrow))*C_IN + ct*64 + ck;
        reinterpret_cast<uint4*>(d)[0] = make_uint4(wds[0], wds[1], wds[2], wds[3]);
        reinterpret_cast<uint4*>(d)[1] = make_uint4(wds[4], wds[5], wds[6], wds[7]);
    }
}

// ---------------------------------------------------------------------------
// Kernel B: convert weights fp32 -> bf16.
// ---------------------------------------------------------------------------
__global__ __launch_bounds__(256, 4)
void convert_w(const float* __restrict__ Wq, const float* __restrict__ Wk,
               const float* __restrict__ Wv,
               ushort_t* __restrict__ Wqb, ushort_t* __restrict__ Wkb,
               ushort_t* __restrict__ Wvb)
{
    const int i4 = (blockIdx.x*256 + threadIdx.x) * 4;
    const float* src; ushort_t* dst; int off;
    if (i4 < 32768)       { src = Wq; dst = Wqb; off = i4; }
    else if (i4 < 65536)  { src = Wk; dst = Wkb; off = i4 - 32768; }
    else                  { src = Wv; dst = Wvb; off = i4 - 65536; }
    float4 v = *reinterpret_cast<const float4*>(src + off);
    ushort4 h;
    h.x = (ushort_t)f2bf(v.x); h.y = (ushort_t)f2bf(v.y);
    h.z = (ushort_t)f2bf(v.z); h.w = (ushort_t)f2bf(v.w);
    *reinterpret_cast<ushort4*>(dst + off) = h;
}

// ---------------------------------------------------------------------------
// Kernel C: MFMA QKV projection (unchanged — passed R5/R8).
// ---------------------------------------------------------------------------
__global__ __launch_bounds__(256, 4)
void proj_mfma(const ushort_t* __restrict__ xT,
               const ushort_t* __restrict__ Wqb, const ushort_t* __restrict__ Wkb,
               const ushort_t* __restrict__ Wvb,
               ushort_t* __restrict__ Qt, ushort_t* __restrict__ Kt,
               ushort_t* __restrict__ Vb)
{
    const int tid = threadIdx.x;
    const int lane = tid & 63, w = tid >> 6;
    const int g = lane >> 4, c16 = lane & 15;
    const int nt = blockIdx.x, mt = blockIdx.y, b = blockIdx.z;
    const int n0 = nt * 128;
    const int kind = (mt == 0) ? 0 : (mt == 1) ? 1 : 2;
    const int wrow0 = (kind == 2) ? (mt - 2) * 64 : 0;
    const ushort_t* Wsrc = (kind == 0) ? Wqb : (kind == 1) ? Wkb : (Wvb + (size_t)wrow0*C_IN);

    __shared__ ushort_t Wl[64*64];
    __shared__ ushort_t Xl[128*64];

    f32x4 acc[8];
    #pragma unroll
    for (int i = 0; i < 8; ++i) acc[i] = (f32x4){0.f,0.f,0.f,0.f};

    const int wrow = tid >> 2, wbc = (tid & 3) * 32;
    const int xrow = tid >> 1, xbc = (tid & 1) * 64;
    const ushort_t* wsrcp = Wsrc + (size_t)wrow*C_IN + wbc/2;
    const ushort_t* xsrcp = xT + ((size_t)(b*N_SP + n0 + xrow))*C_IN + xbc/2;
    char* wdst = (char*)Wl + wrow*128;
    char* xdst = (char*)Xl + xrow*128;
    const int wsz = (wrow & 7) << 4;
    const int xsz = (xrow & 7) << 4;

    uint4 wr[2], xr[4];
    #pragma unroll
    for (int j = 0; j < 2; ++j) wr[j] = *reinterpret_cast<const uint4*>(wsrcp + j*8);
    #pragma unroll
    for (int j = 0; j < 4; ++j) xr[j] = *reinterpret_cast<const uint4*>(xsrcp + j*8);

    const int aswz = (c16 & 7) << 4;

    for (int ks = 0; ks < 8; ++ks) {
        if (ks) __syncthreads();
        #pragma unroll
        for (int j = 0; j < 2; ++j)
            *reinterpret_cast<uint4*>(wdst + ((wbc + j*16) ^ wsz)) = wr[j];
        #pragma unroll
        for (int j = 0; j < 4; ++j)
            *reinterpret_cast<uint4*>(xdst + ((xbc + j*16) ^ xsz)) = xr[j];
        if (ks + 1 < 8) {
            const int k0 = (ks + 1) * 64;
            #pragma unroll
            for (int j = 0; j < 2; ++j) wr[j] = *reinterpret_cast<const uint4*>(wsrcp + k0 + j*8);
            #pragma unroll
            for (int j = 0; j < 4; ++j) xr[j] = *reinterpret_cast<const uint4*>(xsrcp + k0 + j*8);
        }
        __syncthreads();

        __builtin_amdgcn_s_setprio(1);
        if (kind < 2) {
            bf16x8 af[2][2], bfr[4][2];
            #pragma unroll
            for (int m2 = 0; m2 < 2; ++m2)
                #pragma unroll
                for (int kh = 0; kh < 2; ++kh)
                    af[m2][kh] = *reinterpret_cast<const bf16x8*>(
                        (char*)Xl + (w*32 + m2*16 + c16)*128 + ((kh*64 + g*16) ^ aswz));
            #pragma unroll
            for (int ot = 0; ot < 4; ++ot)
                #pragma unroll
                for (int kh = 0; kh < 2; ++kh)
                    bfr[ot][kh] = *reinterpret_cast<const bf16x8*>(
                        (char*)Wl + (ot*16 + c16)*128 + ((kh*64 + g*16) ^ aswz));
            #pragma unroll
            for (int m2 = 0; m2 < 2; ++m2)
                #pragma unroll
                for (int ot = 0; ot < 4; ++ot) {
                    acc[m2*4+ot] = __builtin_amdgcn_mfma_f32_16x16x32_bf16(af[m2][0], bfr[ot][0], acc[m2*4+ot], 0, 0, 0);
                    acc[m2*4+ot] = __builtin_amdgcn_mfma_f32_16x16x32_bf16(af[m2][1], bfr[ot][1], acc[m2*4+ot], 0, 0, 0);
                }
        } else {
            bf16x8 af[4][2], bfr[2][2];
            #pragma unroll
            for (int ct = 0; ct < 4; ++ct)
                #pragma unroll
                for (int kh = 0; kh < 2; ++kh)
                    af[ct][kh] = *reinterpret_cast<const bf16x8*>(
                        (char*)Wl + (ct*16 + c16)*128 + ((kh*64 + g*16) ^ aswz));
            #pragma unroll
            for (int n2 = 0; n2 < 2; ++n2)
                #pragma unroll
                for (int kh = 0; kh < 2; ++kh)
                    bfr[n2][kh] = *reinterpret_cast<const bf16x8*>(
                        (char*)Xl + (w*32 + n2*16 + c16)*128 + ((kh*64 + g*16) ^ aswz));
            #pragma unroll
            for (int ct = 0; ct < 4; ++ct)
                #pragma unroll
                for (int n2 = 0; n2 < 2; ++n2) {
                    acc[ct*2+n2] = __builtin_amdgcn_mfma_f32_16x16x32_bf16(af[ct][0], bfr[n2][0], acc[ct*2+n2], 0, 0, 0);
                    acc[ct*2+n2] = __builtin_amdgcn_mfma_f32_16x16x32_bf16(af[ct][1], bfr[n2][1], acc[ct*2+n2], 0, 0, 0);
                }
        }
        __builtin_amdgcn_s_setprio(0);
    }

    if (kind < 2) {
        ushort_t* O = (kind == 0 ? Qt : Kt) + (size_t)b*N_SP*CQ;
        #pragma unroll
        for (int m2 = 0; m2 < 2; ++m2)
            #pragma unroll
            for (int ot = 0; ot < 4; ++ot)
                #pragma unroll
                for (int q = 0; q < 4; ++q) {
                    const int n = n0 + w*32 + m2*16 + g*4 + q;
                    O[(size_t)n*CQ + ot*16 + c16] = (ushort_t)f2bf(acc[m2*4+ot][q]);
                }
    } else {
        #pragma unroll
        for (int ct = 0; ct < 4; ++ct)
            #pragma unroll
            for (int n2 = 0; n2 < 2; ++n2)
                #pragma unroll
                for (int q = 0; q < 4; ++q) {
                    const int c = wrow0 + ct*16 + g*4 + q;
                    const int n = n0 + w*32 + n2*16 + c16;
                    Vb[((size_t)b*C_IN + c)*N_SP + n] = (ushort_t)f2bf(acc[ct*2+n2][q]);
                }
    }
}

// ---------------------------------------------------------------------------
// Kernel D: MFMA flash attention, K AND V double-buffered in LDS via
// global_load_lds DMA (pre-swizzled source, rule #21), one barrier/iter.
// 256 thr / 4 waves; QT=64 queries, KB=64 keys, CB=128 channels.
// L2 traffic: 1.5 GB total (vs R8's 6 GB); PV reads V from LDS (no exposed
// L2 latency); no register prefetch arrays (no spill path).
// LDS: Q 8K + K 2x8K + V 2x16K + P 8K = 64 KB -> 2 blocks/CU.
// ---------------------------------------------------------------------------
__global__ __launch_bounds__(256, 2)
void attn_mfma(const float* __restrict__ x,
               const ushort_t* __restrict__ Qt,
               const ushort_t* __restrict__ Kt,
               const ushort_t* __restrict__ Vb,
               const float* __restrict__ gamma_p,
               float* __restrict__ out)
{
    const int tid  = threadIdx.x;
    const int lane = tid & 63;
    const int w    = tid >> 6;
    const int g    = lane >> 4;
    const int c16  = lane & 15;

    const int it  = blockIdx.x;       // 64 query tiles of 64
    const int c0  = blockIdx.y * 128; // 4 channel slices
    const int b   = blockIdx.z;
    const int i0g = it * 64;

    __shared__ ushort_t Ql[64*64];        // 8 KB  [query][64ch], swizzled rows
    __shared__ ushort_t Kl[2][64*64];     // 16 KB [key][64ch]
    __shared__ ushort_t Vl[2][128*64];    // 32 KB [chan][64keys]
    __shared__ ushort_t Pl[4][16*64];     // 8 KB  per-wave P transpose

    const char* qsrc = (const char*)(Qt + ((size_t)b*N_SP + i0g)*CQ);
    const char* ksrc = (const char*)(Kt + (size_t)b*N_SP*CQ);
    const char* vsrc = (const char*)(Vb + ((size_t)b*C_IN + c0)*N_SP);

    // ---- prologue: DMA Q, K(0), V(0) ----
    {
        #pragma unroll
        for (int cc = 0; cc < 2; ++cc) {
            const int row = w*16 + cc*8 + (lane >> 3);
            const int bc  = ((lane & 7) * 16) ^ ((row & 7) << 4);
            dma16(qsrc + row*128 + bc, (char*)Ql + w*2048 + cc*1024);
            dma16(ksrc + row*128 + bc, (char*)Kl[0] + w*2048 + cc*1024);
        }
        #pragma unroll
        for (int cc = 0; cc < 4; ++cc) {
            const int row = w*32 + cc*8 + (lane >> 3);   // channel row 0..127
            const int bc  = ((lane & 7) * 16) ^ ((row & 7) << 4);
            dma16(vsrc + (size_t)row*(N_SP*2) + bc, (char*)Vl[0] + w*4096 + cc*1024);
        }
    }
    __asm__ volatile("s_waitcnt vmcnt(0)" ::: "memory");
    __syncthreads();

    const int aswz = (c16 & 7) << 4;
    const int arow = c16 * 128;
    const bf16x8 qf0 = *reinterpret_cast<const bf16x8*>(
        (const char*)Ql + (16*w + c16)*128 + ((g*16) ^ aswz));
    const bf16x8 qf1 = *reinterpret_cast<const bf16x8*>(
        (const char*)Ql + (16*w + c16)*128 + ((64 + g*16) ^ aswz));

    float m_run = -1e30f, l_run = 0.f;
    f32x4 acc[8];
    #pragma unroll
    for (int ct = 0; ct < 8; ++ct) acc[ct] = (f32x4){0.f, 0.f, 0.f, 0.f};

    int cur = 0;
    for (int t = 0; t < N_SP/64; ++t) {
        // A: DMA K(t+1), V(t+1) into alternate buffers (hidden under compute)
        if (t + 1 < N_SP/64) {
            const char* ks = ksrc + (size_t)(t + 1)*64*128;
            #pragma unroll
            for (int cc = 0; cc < 2; ++cc) {
                const int row = w*16 + cc*8 + (lane >> 3);
                const int bc  = ((lane & 7) * 16) ^ ((row & 7) << 4);
                dma16(ks + row*128 + bc, (char*)Kl[cur^1] + w*2048 + cc*1024);
            }
            const char* vs = vsrc + (size_t)(t + 1)*128;   // 64 keys * 2B
            #pragma unroll
            for (int cc = 0; cc < 4; ++cc) {
                const int row = w*32 + cc*8 + (lane >> 3);
                const int bc  = ((lane & 7) * 16) ^ ((row & 7) << 4);
                dma16(vs + (size_t)row*(N_SP*2) + bc, (char*)Vl[cur^1] + w*4096 + cc*1024);
            }
        }

        // B: S^T = K·Q^T from K-LDS
        f32x4 sf[4];
        __builtin_amdgcn_s_setprio(1);
        #pragma unroll
        for (int jt = 0; jt < 4; ++jt) {
            const char* Krow = (const char*)Kl[cur] + (jt*16 + c16)*128;
            const bf16x8 kf0 = *reinterpret_cast<const bf16x8*>(Krow + ((g*16) ^ aswz));
            const bf16x8 kf1 = *reinterpret_cast<const bf16x8*>(Krow + ((64 + g*16) ^ aswz));
            f32x4 z = (f32x4){0.f, 0.f, 0.f, 0.f};
            z = __builtin_amdgcn_mfma_f32_16x16x32_bf16(kf0, qf0, z, 0, 0, 0);
            z = __builtin_amdgcn_mfma_f32_16x16x32_bf16(kf1, qf1, z, 0, 0, 0);
            sf[jt] = z;
        }
        __builtin_amdgcn_s_setprio(0);

        // C: online softmax (lane owns query 16w + c16, 16 j-values)
        float cmax = sf[0][0];
        #pragma unroll
        for (int jt = 0; jt < 4; ++jt)
            #pragma unroll
            for (int q = 0; q < 4; ++q) cmax = fmaxf(cmax, sf[jt][q]);
        cmax = fmaxf(cmax, __shfl_xor(cmax, 16));
        cmax = fmaxf(cmax, __shfl_xor(cmax, 32));
        const float mn = fmaxf(m_run, cmax);
        const float rr = __expf(m_run - mn);
        float csum = 0.f;
        #pragma unroll
        for (int jt = 0; jt < 4; ++jt)
            #pragma unroll
            for (int q = 0; q < 4; ++q) {
                const float p = __expf(sf[jt][q] - mn);
                csum += p;
                sf[jt][q] = p;
            }
        csum += __shfl_xor(csum, 16);
        csum += __shfl_xor(csum, 32);
        l_run = l_run * rr + csum;
        m_run = mn;

        // D: P -> bf16 -> per-wave LDS (A-frag layout), same-wave roundtrip
        #pragma unroll
        for (int jt = 0; jt < 4; ++jt) {
            uint2 pk;
            pk.x = f2bf(sf[jt][0]) | (f2bf(sf[jt][1]) << 16);
            pk.y = f2bf(sf[jt][2]) | (f2bf(sf[jt][3]) << 16);
            *reinterpret_cast<uint2*>((char*)Pl[w] + arow + ((jt*32 + g*8) ^ aswz)) = pk;
        }
        __asm__ volatile("s_waitcnt lgkmcnt(0)" ::: "memory");
        __builtin_amdgcn_sched_barrier(0);
        const bf16x8 pa0 = *reinterpret_cast<const bf16x8*>(
            (const char*)Pl[w] + arow + ((g*16) ^ aswz));
        const bf16x8 pa1 = *reinterpret_cast<const bf16x8*>(
            (const char*)Pl[w] + arow + ((64 + g*16) ^ aswz));

        // E: rescale O
        float rb[4];
        #pragma unroll
        for (int q = 0; q < 4; ++q) rb[q] = __shfl(rr, g*4 + q);
        #pragma unroll
        for (int ct = 0; ct < 8; ++ct)
            #pragma unroll
            for (int q = 0; q < 4; ++q) acc[ct][q] *= rb[q];

        // F: O += P·V^T, V from LDS (conflict-free swizzled ds_read_b128)
        __builtin_amdgcn_s_setprio(1);
        #pragma unroll
        for (int ct = 0; ct < 8; ++ct) {
            const char* Vrow = (const char*)Vl[cur] + (ct*16 + c16)*128;
            const bf16x8 v0 = *reinterpret_cast<const bf16x8*>(Vrow + ((g*16) ^ aswz));
            acc[ct] = __builtin_amdgcn_mfma_f32_16x16x32_bf16(pa0, v0, acc[ct], 0, 0, 0);
        }
        #pragma unroll
        for (int ct = 0; ct < 8; ++ct) {
            const char* Vrow = (const char*)Vl[cur] + (ct*16 + c16)*128;
            const bf16x8 v1 = *reinterpret_cast<const bf16x8*>(Vrow + ((64 + g*16) ^ aswz));
            acc[ct] = __builtin_amdgcn_mfma_f32_16x16x32_bf16(pa1, v1, acc[ct], 0, 0, 0);
        }
        __builtin_amdgcn_s_setprio(0);

        // G: drain DMA, flip buffers
        __asm__ volatile("s_waitcnt vmcnt(0)" ::: "memory");
        __syncthreads();
        cur ^= 1;
    }

    // ---- epilogue: out = gamma*O/l + x ----
    const float gm = gamma_p[0];
    const float li = 1.0f / l_run;
    float lb[4];
    #pragma unroll
    for (int q = 0; q < 4; ++q) lb[q] = __shfl(li, g*4 + q);
    #pragma unroll
    for (int ct = 0; ct < 8; ++ct) {
        const size_t base = ((size_t)b*C_IN + c0 + ct*16 + c16)*N_SP + i0g + 16*w + g*4;
        const float4 xv = *reinterpret_cast<const float4*>(x + base);
        float4 ov;
        ov.x = fmaf(gm, acc[ct][0]*lb[0], xv.x);
        ov.y = fmaf(gm, acc[ct][1]*lb[1], xv.y);
        ov.z = fmaf(gm, acc[ct][2]*lb[2], xv.z);
        ov.w = fmaf(gm, acc[ct][3]*lb[3], xv.w);
        *reinterpret_cast<float4*>(out + base) = ov;
    }
}

extern "C" void kernel_launch(void* const* d_in, const int* in_sizes, int n_in,
                              void* d_out, int out_size, void* d_ws, size_t ws_size,
                              hipStream_t stream)
{
    (void)in_sizes; (void)n_in; (void)out_size; (void)ws_size;
    const float* x  = (const float*)d_in[0];
    const float* Wq = (const float*)d_in[1];
    const float* Wk = (const float*)d_in[2];
    const float* Wv = (const float*)d_in[3];
    const float* gm = (const float*)d_in[4];
    float* out = (float*)d_out;

    // ws layout (shorts): xT 16.8M | Qt 2M | Kt 2M | V 16.8M | Wqb | Wkb | Wvb
    ushort_t* xT  = (ushort_t*)d_ws;
    ushort_t* Qt  = xT  + (size_t)4*N_SP*C_IN;
    ushort_t* Kt  = Qt  + (size_t)4*N_SP*CQ;
    ushort_t* Vb  = Kt  + (size_t)4*N_SP*CQ;
    ushort_t* Wqb = Vb  + (size_t)4*C_IN*N_SP;
    ushort_t* Wkb = Wqb + (size_t)CQ*C_IN;
    ushort_t* Wvb = Wkb + (size_t)CQ*C_IN;

    dim3 gA(64, 8, 4);
    transpose_x<<<gA, 256, 0, stream>>>(x, xT);
    convert_w<<<320, 256, 0, stream>>>(Wq, Wk, Wv, Wqb, Wkb, Wvb);
    dim3 gC(32, 10, 4);
    proj_mfma<<<gC, 256, 0, stream>>>(xT, Wqb, Wkb, Wvb, Qt, Kt, Vb);
    dim3 gD(64, 4, 4);
    attn_mfma<<<gD, 256, 0, stream>>>(x, Qt, Kt, Vb, gm, out);
}